// Round 1
// baseline (764.385 us; speedup 1.0000x reference)
//
#include <hip/hip_runtime.h>
#include <math.h>

// Problem constants
#define Bn   8
#define Cc   256     // input channels
#define Cin  128     // inter channels
#define Hh   64
#define Ww   64
#define Nn   4096    // H*W
#define Npl  1024    // pooled pixels (32*32)
#define EPSf 1e-5f

// ---------------------------------------------------------------------------
// Kernel 1: fused conv1x1 for g/theta/phi (+ bias) with 2x2 maxpool on g,phi.
//   x:      [B, 256, 64, 64]
//   theta:  [B, 128, 4096]            (full res)
//   gP:     [B, 128, 1024]  (pooled)  -> V
//   phiP:   [B, 128, 1024]  (pooled)  -> K
// Tile: 2 rows x 32 cols of full-res pixels per block (64 pixels), all 384
// output channels. Thread: 4 pixels (float4) x 4 channels register tile.
// Pool: pairs within thread (cols) + __shfl_xor(.,8) (rows).
// ---------------------------------------------------------------------------
__global__ __launch_bounds__(256) void k_conv3(
    const float* __restrict__ x,
    const float* __restrict__ g_w,  const float* __restrict__ g_b,
    const float* __restrict__ th_w, const float* __restrict__ th_b,
    const float* __restrict__ ph_w, const float* __restrict__ ph_b,
    float* __restrict__ theta, float* __restrict__ gP, float* __restrict__ phiP)
{
    __shared__ float xs[Cc * 64];            // [c][p], 64 KB
    const int t    = threadIdx.x;
    const int b    = blockIdx.x >> 6;        // 64 tiles per batch
    const int tile = blockIdx.x & 63;
    const int ty   = tile >> 1;              // 0..31 (pair of full-res rows)
    const int tx   = tile & 1;               // 0..1  (32-col half)
    const int n_base = ty * 2 * Ww + tx * 32;

    // stage x tile: float4 over pixels
    {
        const float4* xg  = (const float4*)x;
        float4*       xs4 = (float4*)xs;
        #pragma unroll
        for (int it = 0; it < 16; ++it) {
            int idx  = t + 256 * it;          // 0..4095 float4 units
            int c    = idx >> 4;              // 0..255
            int p4   = idx & 15;              // pixel quad
            int prow = p4 >> 3;               // 0/1
            int pc4  = p4 & 7;                // col quad within row
            int gidx = ((b * Cc + c) * Nn + n_base + prow * Ww) / 4 + pc4;
            xs4[c * 16 + p4] = xg[gidx];
        }
    }
    __syncthreads();

    const int pg   = t & 15;                 // pixel quad id: pixels pg*4..pg*4+3
    const int og   = t >> 4;                 // 0..15, 24 output channels each
    const int p0   = pg * 4;
    const int prow = p0 >> 5;
    const int pcol = p0 & 31;
    const int n0   = n_base + prow * Ww + pcol;   // 4 consecutive n
    const int np0  = ty * 32 + tx * 16 + pg * 2;  // pooled (valid if pg<8)

    const float4* xs4 = (const float4*)xs;

    for (int ob = 0; ob < 6; ++ob) {
        int o    = og * 24 + ob * 4;          // 4 channels, 4-aligned -> one segment
        int seg  = o >> 7;                    // 0:g  1:theta  2:phi
        int wrow = o - (seg << 7);
        const float4* wb = (const float4*)(seg == 0 ? g_w : (seg == 1 ? th_w : ph_w));
        const float*  bb = (seg == 0 ? g_b : (seg == 1 ? th_b : ph_b));

        float acc[4][4] = {};
        for (int c4 = 0; c4 < 64; ++c4) {
            float4 xa = xs4[(c4 * 4 + 0) * 16 + pg];
            float4 xb = xs4[(c4 * 4 + 1) * 16 + pg];
            float4 xc = xs4[(c4 * 4 + 2) * 16 + pg];
            float4 xd = xs4[(c4 * 4 + 3) * 16 + pg];
            #pragma unroll
            for (int i = 0; i < 4; ++i) {
                float4 wv = wb[(wrow + i) * 64 + c4];
                acc[i][0] += wv.x * xa.x + wv.y * xb.x + wv.z * xc.x + wv.w * xd.x;
                acc[i][1] += wv.x * xa.y + wv.y * xb.y + wv.z * xc.y + wv.w * xd.y;
                acc[i][2] += wv.x * xa.z + wv.y * xb.z + wv.z * xc.z + wv.w * xd.z;
                acc[i][3] += wv.x * xa.w + wv.y * xb.w + wv.z * xc.w + wv.w * xd.w;
            }
        }

        if (seg == 1) {                        // theta: full-res, transposed layout [B,Ci,N]
            #pragma unroll
            for (int i = 0; i < 4; ++i) {
                float bias = bb[wrow + i];
                float4 v = make_float4(acc[i][0] + bias, acc[i][1] + bias,
                                       acc[i][2] + bias, acc[i][3] + bias);
                *(float4*)(theta + (size_t)(b * Cin + wrow + i) * Nn + n0) = v;
            }
        } else {                               // g / phi: 2x2 maxpool then store
            float* dst = (seg == 0) ? gP : phiP;
            #pragma unroll
            for (int i = 0; i < 4; ++i) {
                float bias = bb[wrow + i];
                float m01 = fmaxf(acc[i][0], acc[i][1]);
                float m23 = fmaxf(acc[i][2], acc[i][3]);
                float r01 = fmaxf(m01, __shfl_xor(m01, 8, 64));  // row pair (prow flip)
                float r23 = fmaxf(m23, __shfl_xor(m23, 8, 64));
                if (pg < 8) {
                    float2 v = make_float2(r01 + bias, r23 + bias);
                    *(float2*)(dst + (size_t)(b * Cin + wrow + i) * Npl + np0) = v;
                }
            }
        }
    }
}

// ---------------------------------------------------------------------------
// Kernel 2: flash-style attention with online softmax (exact, fp32).
//   Q = theta [B,Ci,N] (read transposed), K = phiP, V = gP ([B,Ci,Np]).
//   y [B, N, Ci]  (pixel-major rows for kernel 3)
// Block: 32 Q rows, 256 threads. Chunk: 64 keys. LDS ~58 KB -> 2 blocks/CU.
// ---------------------------------------------------------------------------
#define QPAD 132
#define KPAD 132
#define SPAD 68

__global__ __launch_bounds__(256) void k_attn(
    const float* __restrict__ theta, const float* __restrict__ phiP,
    const float* __restrict__ gP, float* __restrict__ y)
{
    __shared__ float Qs[32 * QPAD];        // 16.9 KB
    __shared__ float KVs[64 * KPAD];       // 33.8 KB (K then V, per chunk)
    __shared__ float Ss[32 * SPAD];        // 8.7 KB  (score chunk / exp'd P)
    __shared__ float Mrow[32], Lrow[32], Arow[32];

    const int t  = threadIdx.x;
    const int b  = blockIdx.x >> 7;        // 128 q-blocks per batch
    const int qb = blockIdx.x & 127;
    const int n0 = qb * 32;

    // stage Q (transpose [Ci,N] -> [q][ci])
    #pragma unroll
    for (int it = 0; it < 16; ++it) {
        int idx = t + 256 * it;            // 0..4095
        int ci  = idx >> 5;
        int qi  = idx & 31;
        Qs[qi * QPAD + ci] = theta[(size_t)(b * Cin + ci) * Nn + n0 + qi];
    }
    if (t < 32) { Mrow[t] = -1e30f; Lrow[t] = 0.f; }

    const int mg  = t & 15;                // score tile: m = mg*4+j
    const int qg  = t >> 4;                // 0..15:      q = qg*2+i
    const int cg  = t & 31;                // PV tile: c = cg*4..+3
    const int qg2 = t >> 5;                // 0..7:    q = qg2*4..+3

    float acc[4][4] = {};                  // y accumulator (4q x 4c)

    for (int ch = 0; ch < 16; ++ch) {
        __syncthreads();                                   // (a) prev PV done
        // stage K chunk, transposed: KVs[mi][ci]
        #pragma unroll
        for (int it = 0; it < 32; ++it) {
            int idx = t + 256 * it;        // 0..8191
            int ci  = idx >> 6;
            int mi  = idx & 63;
            KVs[mi * KPAD + ci] = phiP[(size_t)(b * Cin + ci) * Npl + ch * 64 + mi];
        }
        __syncthreads();                                   // (b)
        // S chunk: s[q][m] = Q[q]·K[m]
        {
            const float4* K4 = (const float4*)KVs;
            const float4* Q4 = (const float4*)Qs;
            float a0[4] = {}, a1[4] = {};
            for (int c4 = 0; c4 < 32; ++c4) {
                float4 q0 = Q4[(qg * 2 + 0) * (QPAD / 4) + c4];
                float4 q1 = Q4[(qg * 2 + 1) * (QPAD / 4) + c4];
                #pragma unroll
                for (int j = 0; j < 4; ++j) {
                    float4 kv = K4[(mg * 4 + j) * (KPAD / 4) + c4];
                    a0[j] += q0.x * kv.x + q0.y * kv.y + q0.z * kv.z + q0.w * kv.w;
                    a1[j] += q1.x * kv.x + q1.y * kv.y + q1.z * kv.z + q1.w * kv.w;
                }
            }
            *(float4*)(Ss + (qg * 2 + 0) * SPAD + mg * 4) = make_float4(a0[0], a0[1], a0[2], a0[3]);
            *(float4*)(Ss + (qg * 2 + 1) * SPAD + mg * 4) = make_float4(a1[0], a1[1], a1[2], a1[3]);
        }
        __syncthreads();                                   // (c) S ready, KVs free
        // stage V chunk (overwrites K) — independent of stats below
        #pragma unroll
        for (int it = 0; it < 32; ++it) {
            int idx = t + 256 * it;
            int ci  = idx >> 6;
            int mi  = idx & 63;
            KVs[mi * KPAD + ci] = gP[(size_t)(b * Cin + ci) * Npl + ch * 64 + mi];
        }
        // online-softmax row stats; exp-ify Ss in place
        {
            int r  = t >> 3;               // 0..31
            int l8 = t & 7;
            float mx = -1e30f;
            #pragma unroll
            for (int j = 0; j < 8; ++j) mx = fmaxf(mx, Ss[r * SPAD + l8 + 8 * j]);
            #pragma unroll
            for (int o = 4; o; o >>= 1) mx = fmaxf(mx, __shfl_xor(mx, o, 8));
            float m_old = Mrow[r];
            float m_new = fmaxf(m_old, mx);
            float rsum = 0.f;
            #pragma unroll
            for (int j = 0; j < 8; ++j) {
                float e = __expf(Ss[r * SPAD + l8 + 8 * j] - m_new);
                Ss[r * SPAD + l8 + 8 * j] = e;
                rsum += e;
            }
            #pragma unroll
            for (int o = 4; o; o >>= 1) rsum += __shfl_xor(rsum, o, 8);
            if (l8 == 0) {
                float alpha = __expf(m_old - m_new);
                Arow[r] = alpha;
                Mrow[r] = m_new;
                Lrow[r] = Lrow[r] * alpha + rsum;
            }
        }
        __syncthreads();                                   // (d)
        // PV accumulate: acc = acc*alpha + P_chunk @ V_chunk
        {
            const float4* V4 = (const float4*)KVs;
            #pragma unroll
            for (int i = 0; i < 4; ++i) {
                float al = Arow[qg2 * 4 + i];
                acc[i][0] *= al; acc[i][1] *= al; acc[i][2] *= al; acc[i][3] *= al;
            }
            for (int m = 0; m < 64; ++m) {
                float4 vv = V4[m * (KPAD / 4) + cg];
                #pragma unroll
                for (int i = 0; i < 4; ++i) {
                    float p = Ss[(qg2 * 4 + i) * SPAD + m];
                    acc[i][0] += p * vv.x; acc[i][1] += p * vv.y;
                    acc[i][2] += p * vv.z; acc[i][3] += p * vv.w;
                }
            }
        }
    }

    // normalize and store y [B, N, Ci]
    #pragma unroll
    for (int i = 0; i < 4; ++i) {
        int q = qg2 * 4 + i;
        float il = 1.0f / Lrow[q];
        float4 o = make_float4(acc[i][0] * il, acc[i][1] * il,
                               acc[i][2] * il, acc[i][3] * il);
        *(float4*)(y + (size_t)(b * Nn + n0 + q) * Cin + cg * 4) = o;
    }
}

// ---------------------------------------------------------------------------
// Kernel 3: out = BN(conv1x1(y, W_w) + W_b) + x
//   y [B, N, 128], W_w [256,128], out/x [B,256,4096]
// Block: 64 pixels (one image row), all 256 channels. Thread: 1 pixel x 64 ch.
// ---------------------------------------------------------------------------
#define YPAD 132

__global__ __launch_bounds__(256) void k_out(
    const float* __restrict__ y, const float* __restrict__ x,
    const float* __restrict__ W_w, const float* __restrict__ W_b,
    const float* __restrict__ gamma, const float* __restrict__ beta,
    const float* __restrict__ mean,  const float* __restrict__ var,
    float* __restrict__ out)
{
    __shared__ float ys[64 * YPAD];        // 33.8 KB
    const int t   = threadIdx.x;
    const int b   = blockIdx.x >> 6;
    const int row = blockIdx.x & 63;
    const int n0  = row * 64;

    {
        const float4* yg = (const float4*)y;
        #pragma unroll
        for (int it = 0; it < 8; ++it) {
            int idx = t + 256 * it;        // 0..2047 float4
            int p   = idx >> 5;
            int c4  = idx & 31;
            float4 v = yg[(size_t)(b * Nn + n0 + p) * (Cin / 4) + c4];
            *(float4*)(ys + p * YPAD + c4 * 4) = v;
        }
    }
    __syncthreads();

    const int p  = t & 63;                 // pixel (lane) -> coalesced I/O
    const int og = t >> 6;                 // 4 groups x 64 channels (wave-uniform)
    const float4* ysr = (const float4*)(ys + p * YPAD);
    const float4* w4  = (const float4*)W_w;

    for (int os = 0; os < 4; ++os) {
        int obase = og * 64 + os * 16;
        float acc[16] = {};
        for (int cc = 0; cc < 4; ++cc) {   // 4 chunks of 32 channels-in
            float4 yr[8];
            #pragma unroll
            for (int k = 0; k < 8; ++k) yr[k] = ysr[cc * 8 + k];
            #pragma unroll
            for (int oi = 0; oi < 16; ++oi) {
                int o = obase + oi;
                #pragma unroll
                for (int k = 0; k < 8; ++k) {
                    float4 wv = w4[o * 32 + cc * 8 + k];
                    acc[oi] += wv.x * yr[k].x + wv.y * yr[k].y
                             + wv.z * yr[k].z + wv.w * yr[k].w;
                }
            }
        }
        #pragma unroll
        for (int oi = 0; oi < 16; ++oi) {
            int o = obase + oi;
            float inv = gamma[o] * rsqrtf(var[o] + EPSf);
            float v   = (acc[oi] + W_b[o] - mean[o]) * inv + beta[o];
            size_t gi = (size_t)(b * Cc + o) * Nn + n0 + p;
            out[gi] = v + x[gi];
        }
    }
}

// ---------------------------------------------------------------------------
extern "C" void kernel_launch(void* const* d_in, const int* in_sizes, int n_in,
                              void* d_out, int out_size, void* d_ws, size_t ws_size,
                              hipStream_t stream) {
    const float* x    = (const float*)d_in[0];
    const float* g_w  = (const float*)d_in[1];
    const float* g_b  = (const float*)d_in[2];
    const float* th_w = (const float*)d_in[3];
    const float* th_b = (const float*)d_in[4];
    const float* ph_w = (const float*)d_in[5];
    const float* ph_b = (const float*)d_in[6];
    const float* W_w  = (const float*)d_in[7];
    const float* W_b  = (const float*)d_in[8];
    const float* gmm  = (const float*)d_in[9];
    const float* bta  = (const float*)d_in[10];
    const float* mmn  = (const float*)d_in[11];
    const float* vvr  = (const float*)d_in[12];
    float* out = (float*)d_out;

    float* ws    = (float*)d_ws;
    float* theta = ws;                       // 8*128*4096 = 4,194,304 f
    float* phiP  = theta + 4194304;          // 8*128*1024 = 1,048,576 f
    float* gP    = phiP + 1048576;           // 1,048,576 f
    float* y     = gP + 1048576;             // 4,194,304 f   (total ~42 MB)

    k_conv3<<<dim3(Bn * 64), dim3(256), 0, stream>>>(
        x, g_w, g_b, th_w, th_b, ph_w, ph_b, theta, gP, phiP);
    k_attn<<<dim3(Bn * 128), dim3(256), 0, stream>>>(theta, phiP, gP, y);
    k_out<<<dim3(Bn * 64), dim3(256), 0, stream>>>(
        y, x, W_w, W_b, gmm, bta, mmn, vvr, out);
}

// Round 3
// 395.767 us; speedup vs baseline: 1.9314x; 1.9314x over previous
//
#include <hip/hip_runtime.h>
#include <math.h>

// Problem constants
#define Bn   8
#define Cc   256     // input channels
#define Cin  128     // inter channels
#define Hh   64
#define Ww   64
#define Nn   4096    // H*W
#define Npl  1024    // pooled pixels (32*32)
#define EPSf 1e-5f

typedef __attribute__((ext_vector_type(8))) short short8;    // 8 bf16 (4 VGPRs)
typedef __attribute__((ext_vector_type(4))) float floatx4;   // MFMA C/D

__device__ __forceinline__ unsigned short f2bf(float f) {
    unsigned int u = __float_as_uint(f);
    u += 0x7fffu + ((u >> 16) & 1u);     // round-to-nearest-even
    return (unsigned short)(u >> 16);
}

// ---------------------------------------------------------------------------
// Kernel 1: fused conv1x1 for g/theta/phi (+ bias) with 2x2 maxpool on g,phi.
// fp32 compute (VALU), bf16 outputs in MFMA-friendly layouts:
//   thetaT: [B, 4096, 128] bf16 (pixel-major -> Q rows)
//   phiPt:  [B, 1024, 128] bf16 (pixel-major -> K rows)
//   gPc:    [B, 128, 1024] bf16 (channel-major -> V^T staging)
// ---------------------------------------------------------------------------
__global__ __launch_bounds__(256) void k_conv3(
    const float* __restrict__ x,
    const float* __restrict__ g_w,  const float* __restrict__ g_b,
    const float* __restrict__ th_w, const float* __restrict__ th_b,
    const float* __restrict__ ph_w, const float* __restrict__ ph_b,
    unsigned short* __restrict__ thetaT,
    unsigned short* __restrict__ gPc,
    unsigned short* __restrict__ phiPt)
{
    __shared__ float xs[Cc * 64];            // [c][p], 64 KB
    const int t    = threadIdx.x;
    const int b    = blockIdx.x >> 6;        // 64 tiles per batch
    const int tile = blockIdx.x & 63;
    const int ty   = tile >> 1;              // 0..31 (pair of full-res rows)
    const int tx   = tile & 1;               // 0..1  (32-col half)
    const int n_base = ty * 2 * Ww + tx * 32;

    // stage x tile: float4 over pixels
    {
        const float4* xg  = (const float4*)x;
        float4*       xs4 = (float4*)xs;
        #pragma unroll
        for (int it = 0; it < 16; ++it) {
            int idx  = t + 256 * it;          // 0..4095 float4 units
            int c    = idx >> 4;              // 0..255
            int p4   = idx & 15;              // pixel quad
            int prow = p4 >> 3;               // 0/1
            int pc4  = p4 & 7;                // col quad within row
            int gidx = ((b * Cc + c) * Nn + n_base + prow * Ww) / 4 + pc4;
            xs4[c * 16 + p4] = xg[gidx];
        }
    }
    __syncthreads();

    const int pg   = t & 15;                 // pixel quad id: pixels pg*4..pg*4+3
    const int og   = t >> 4;                 // 0..15, 24 output channels each
    const int p0   = pg * 4;
    const int prow = p0 >> 5;
    const int pcol = p0 & 31;
    const int n0   = n_base + prow * Ww + pcol;   // 4 consecutive n
    const int np0  = ty * 32 + tx * 16 + pg * 2;  // pooled (valid if pg<8)

    const float4* xs4 = (const float4*)xs;

    for (int ob = 0; ob < 6; ++ob) {
        int o    = og * 24 + ob * 4;          // 4 channels, 4-aligned -> one segment
        int seg  = o >> 7;                    // 0:g  1:theta  2:phi
        int wrow = o - (seg << 7);
        const float4* wb = (const float4*)(seg == 0 ? g_w : (seg == 1 ? th_w : ph_w));
        const float*  bb = (seg == 0 ? g_b : (seg == 1 ? th_b : ph_b));

        float acc[4][4] = {};
        for (int c4 = 0; c4 < 64; ++c4) {
            float4 xa = xs4[(c4 * 4 + 0) * 16 + pg];
            float4 xb = xs4[(c4 * 4 + 1) * 16 + pg];
            float4 xc = xs4[(c4 * 4 + 2) * 16 + pg];
            float4 xd = xs4[(c4 * 4 + 3) * 16 + pg];
            #pragma unroll
            for (int i = 0; i < 4; ++i) {
                float4 wv = wb[(wrow + i) * 64 + c4];
                acc[i][0] += wv.x * xa.x + wv.y * xb.x + wv.z * xc.x + wv.w * xd.x;
                acc[i][1] += wv.x * xa.y + wv.y * xb.y + wv.z * xc.y + wv.w * xd.y;
                acc[i][2] += wv.x * xa.z + wv.y * xb.z + wv.z * xc.z + wv.w * xd.z;
                acc[i][3] += wv.x * xa.w + wv.y * xb.w + wv.z * xc.w + wv.w * xd.w;
            }
        }

        if (seg == 1) {                        // theta -> thetaT [B,N,128] bf16
            float b0 = bb[wrow], b1 = bb[wrow + 1], b2 = bb[wrow + 2], b3 = bb[wrow + 3];
            #pragma unroll
            for (int j = 0; j < 4; ++j) {
                ushort4 v;
                v.x = f2bf(acc[0][j] + b0);
                v.y = f2bf(acc[1][j] + b1);
                v.z = f2bf(acc[2][j] + b2);
                v.w = f2bf(acc[3][j] + b3);
                *(ushort4*)&thetaT[((size_t)b * Nn + n0 + j) * Cin + wrow] = v;
            }
        } else {                               // g / phi: 2x2 maxpool then store bf16
            float v0[4], v1[4];
            #pragma unroll
            for (int i = 0; i < 4; ++i) {
                float bias = bb[wrow + i];
                float m01 = fmaxf(acc[i][0], acc[i][1]);
                float m23 = fmaxf(acc[i][2], acc[i][3]);
                v0[i] = fmaxf(m01, __shfl_xor(m01, 8, 64)) + bias;  // pooled pixel np0
                v1[i] = fmaxf(m23, __shfl_xor(m23, 8, 64)) + bias;  // pooled pixel np0+1
            }
            if (pg < 8) {
                if (seg == 0) {                // g -> gPc [B,128,1024] channel-major
                    #pragma unroll
                    for (int i = 0; i < 4; ++i) {
                        ushort2 vv;
                        vv.x = f2bf(v0[i]); vv.y = f2bf(v1[i]);
                        *(ushort2*)&gPc[((size_t)b * Cin + wrow + i) * Npl + np0] = vv;
                    }
                } else {                       // phi -> phiPt [B,1024,128] pixel-major
                    ushort4 a, c;
                    a.x = f2bf(v0[0]); a.y = f2bf(v0[1]); a.z = f2bf(v0[2]); a.w = f2bf(v0[3]);
                    c.x = f2bf(v1[0]); c.y = f2bf(v1[1]); c.z = f2bf(v1[2]); c.w = f2bf(v1[3]);
                    *(ushort4*)&phiPt[((size_t)b * Npl + np0) * Cin + wrow] = a;
                    *(ushort4*)&phiPt[((size_t)b * Npl + np0 + 1) * Cin + wrow] = c;
                }
            }
        }
    }
}

// ---------------------------------------------------------------------------
// Kernel 2: flash attention, bf16 MFMA (16x16x32), online softmax in registers.
//   Q = thetaT [B,N,128], K = phiPt [B,Np,128], V^T = gPc [B,128,Np]
//   y [B, N, 128] fp32 (pixel-major for kernel 3)
// Block: 64 Q rows, 4 waves (16 q-rows each). Chunk: 64 keys. 16 chunks.
// MFMA frag mapping (verified, learn_hip m89/m120):
//   A[m=lane&15][k=quad*8+j], B[k=quad*8+j][n=lane&15], D[row=quad*4+r][col=lane&15]
// LDS pads: row strides 136/72 bf16 = 68/36 dwords == 4 mod 32 -> 2-way (free).
// Staging: each tile is 8192 bf16; 256 thr x 8 bf16 = 2048/iter -> 4 iters.
// ---------------------------------------------------------------------------
#define DPAD 136
#define VPAD 72
#define PPAD 72

__global__ __launch_bounds__(256) void k_attn(
    const unsigned short* __restrict__ thetaT,
    const unsigned short* __restrict__ phiPt,
    const unsigned short* __restrict__ gPc,
    float* __restrict__ y)
{
    __shared__ __align__(16) unsigned short Qs[64 * DPAD];     // 17.0 KB
    __shared__ __align__(16) unsigned short Ks[64 * DPAD];     // 17.0 KB
    __shared__ __align__(16) unsigned short Vt[Cin * VPAD];    // 18.0 KB
    __shared__ __align__(16) unsigned short Ps[4][16 * PPAD];  // 9.0 KB (per-wave)

    const int t    = threadIdx.x;
    const int w    = t >> 6;        // wave id: q rows w*16..w*16+15
    const int l    = t & 63;
    const int quad = l >> 4;
    const int l16  = l & 15;
    const int b    = blockIdx.x >> 6;
    const int qb   = blockIdx.x & 63;
    const int n0   = qb * 64;

    // stage Q tile (64 rows x 128 bf16): 4 iters x 2048 bf16
    #pragma unroll
    for (int it = 0; it < 4; ++it) {
        int idx = t + 256 * it;          // 0..1023
        int q = idx >> 4, d8 = idx & 15;
        *(uint4*)&Qs[q * DPAD + d8 * 8] =
            *(const uint4*)&thetaT[((size_t)b * Nn + n0 + q) * Cin + d8 * 8];
    }
    __syncthreads();

    // Q A-fragments (chunk-invariant): qf[kd] = Q[w*16+l16][kd*32 + quad*8 ..+8]
    short8 qf[4];
    #pragma unroll
    for (int kd = 0; kd < 4; ++kd)
        qf[kd] = *(const short8*)&Qs[(w * 16 + l16) * DPAD + kd * 32 + quad * 8];

    floatx4 yacc[8] = {};                     // Y[16 q x 128 c] per wave
    float mi[4] = {-1e30f, -1e30f, -1e30f, -1e30f};
    float li[4] = {0.f, 0.f, 0.f, 0.f};

    for (int ch = 0; ch < 16; ++ch) {
        __syncthreads();                      // prior chunk's K/V frag reads done
        // stage K chunk: [64 m x 128 d] bf16
        #pragma unroll
        for (int it = 0; it < 4; ++it) {
            int idx = t + 256 * it;          // 0..1023
            int m = idx >> 4, d8 = idx & 15;
            *(uint4*)&Ks[m * DPAD + d8 * 8] =
                *(const uint4*)&phiPt[((size_t)b * Npl + ch * 64 + m) * Cin + d8 * 8];
        }
        // stage V^T chunk: Vt[c][m] (128 c x 64 m), straight from channel-major gPc
        #pragma unroll
        for (int it = 0; it < 4; ++it) {
            int idx = t + 256 * it;          // 0..1023
            int c = idx >> 3, m8 = idx & 7;
            *(uint4*)&Vt[c * VPAD + m8 * 8] =
                *(const uint4*)&gPc[((size_t)b * Cin + c) * Npl + ch * 64 + m8 * 8];
        }
        __syncthreads();

        // S[16 q x 64 m] = Q K^T : 4 m-tiles x 4 k-depth MFMAs
        floatx4 sacc[4] = {};
        #pragma unroll
        for (int mt = 0; mt < 4; ++mt) {
            #pragma unroll
            for (int kd = 0; kd < 4; ++kd) {
                short8 kf = *(const short8*)&Ks[(mt * 16 + l16) * DPAD + kd * 32 + quad * 8];
                sacc[mt] = __builtin_amdgcn_mfma_f32_16x16x32_bf16(qf[kd], kf, sacc[mt], 0, 0, 0);
            }
        }

        // online softmax: row q = quad*4+r lives on 16 lanes (fixed quad), reg r
        float pv[4][4];                       // [mt][r]
        #pragma unroll
        for (int r = 0; r < 4; ++r) {
            float mx = fmaxf(fmaxf(sacc[0][r], sacc[1][r]), fmaxf(sacc[2][r], sacc[3][r]));
            #pragma unroll
            for (int o = 1; o < 16; o <<= 1) mx = fmaxf(mx, __shfl_xor(mx, o, 64));
            float mnew  = fmaxf(mi[r], mx);
            float alpha = __expf(mi[r] - mnew);
            mi[r] = mnew;
            float rs = 0.f;
            #pragma unroll
            for (int mt = 0; mt < 4; ++mt) {
                float e = __expf(sacc[mt][r] - mnew);
                pv[mt][r] = e; rs += e;
            }
            #pragma unroll
            for (int o = 1; o < 16; o <<= 1) rs += __shfl_xor(rs, o, 64);
            li[r] = li[r] * alpha + rs;
            #pragma unroll
            for (int ct = 0; ct < 8; ++ct) yacc[ct][r] *= alpha;
        }

        // P: C/D layout -> LDS (per-wave, no block sync needed) -> A layout
        #pragma unroll
        for (int mt = 0; mt < 4; ++mt)
            #pragma unroll
            for (int r = 0; r < 4; ++r)
                Ps[w][(quad * 4 + r) * PPAD + mt * 16 + l16] = f2bf(pv[mt][r]);

        short8 pf[2];
        #pragma unroll
        for (int kd = 0; kd < 2; ++kd)
            pf[kd] = *(const short8*)&Ps[w][l16 * PPAD + kd * 32 + quad * 8];

        // Y += P V : 8 c-tiles x 2 k-depth MFMAs
        #pragma unroll
        for (int ct = 0; ct < 8; ++ct) {
            #pragma unroll
            for (int kd = 0; kd < 2; ++kd) {
                short8 vf = *(const short8*)&Vt[(ct * 16 + l16) * VPAD + kd * 32 + quad * 8];
                yacc[ct] = __builtin_amdgcn_mfma_f32_16x16x32_bf16(pf[kd], vf, yacc[ct], 0, 0, 0);
            }
        }
    }

    // normalize and store y [B,N,128] fp32
    #pragma unroll
    for (int r = 0; r < 4; ++r) {
        float il = 1.0f / li[r];
        int q = n0 + w * 16 + quad * 4 + r;
        float* yr = y + ((size_t)b * Nn + q) * Cin;
        #pragma unroll
        for (int ct = 0; ct < 8; ++ct)
            yr[ct * 16 + l16] = yacc[ct][r] * il;
    }
}

// ---------------------------------------------------------------------------
// Kernel 3: out = BN(conv1x1(y, W_w) + W_b) + x
//   y [B, N, 128], W_w [256,128], out/x [B,256,4096]
// ---------------------------------------------------------------------------
#define YPAD 132

__global__ __launch_bounds__(256) void k_out(
    const float* __restrict__ y, const float* __restrict__ x,
    const float* __restrict__ W_w, const float* __restrict__ W_b,
    const float* __restrict__ gamma, const float* __restrict__ beta,
    const float* __restrict__ mean,  const float* __restrict__ var,
    float* __restrict__ out)
{
    __shared__ float ys[64 * YPAD];        // 33.8 KB
    const int t   = threadIdx.x;
    const int b   = blockIdx.x >> 6;
    const int row = blockIdx.x & 63;
    const int n0  = row * 64;

    {
        const float4* yg = (const float4*)y;
        #pragma unroll
        for (int it = 0; it < 8; ++it) {
            int idx = t + 256 * it;        // 0..2047 float4
            int p   = idx >> 5;
            int c4  = idx & 31;
            float4 v = yg[(size_t)(b * Nn + n0 + p) * (Cin / 4) + c4];
            *(float4*)(ys + p * YPAD + c4 * 4) = v;
        }
    }
    __syncthreads();

    const int p  = t & 63;                 // pixel (lane) -> coalesced I/O
    const int og = t >> 6;                 // 4 groups x 64 channels (wave-uniform)
    const float4* ysr = (const float4*)(ys + p * YPAD);
    const float4* w4  = (const float4*)W_w;

    for (int os = 0; os < 4; ++os) {
        int obase = og * 64 + os * 16;
        float acc[16] = {};
        for (int cc = 0; cc < 4; ++cc) {   // 4 chunks of 32 channels-in
            float4 yr[8];
            #pragma unroll
            for (int k = 0; k < 8; ++k) yr[k] = ysr[cc * 8 + k];
            #pragma unroll
            for (int oi = 0; oi < 16; ++oi) {
                int o = obase + oi;
                #pragma unroll
                for (int k = 0; k < 8; ++k) {
                    float4 wv = w4[o * 32 + cc * 8 + k];
                    acc[oi] += wv.x * yr[k].x + wv.y * yr[k].y
                             + wv.z * yr[k].z + wv.w * yr[k].w;
                }
            }
        }
        #pragma unroll
        for (int oi = 0; oi < 16; ++oi) {
            int o = obase + oi;
            float inv = gamma[o] * rsqrtf(var[o] + EPSf);
            float v   = (acc[oi] + W_b[o] - mean[o]) * inv + beta[o];
            size_t gi = (size_t)(b * Cc + o) * Nn + n0 + p;
            out[gi] = v + x[gi];
        }
    }
}

// ---------------------------------------------------------------------------
extern "C" void kernel_launch(void* const* d_in, const int* in_sizes, int n_in,
                              void* d_out, int out_size, void* d_ws, size_t ws_size,
                              hipStream_t stream) {
    const float* x    = (const float*)d_in[0];
    const float* g_w  = (const float*)d_in[1];
    const float* g_b  = (const float*)d_in[2];
    const float* th_w = (const float*)d_in[3];
    const float* th_b = (const float*)d_in[4];
    const float* ph_w = (const float*)d_in[5];
    const float* ph_b = (const float*)d_in[6];
    const float* W_w  = (const float*)d_in[7];
    const float* W_b  = (const float*)d_in[8];
    const float* gmm  = (const float*)d_in[9];
    const float* bta  = (const float*)d_in[10];
    const float* mmn  = (const float*)d_in[11];
    const float* vvr  = (const float*)d_in[12];
    float* out = (float*)d_out;

    unsigned short* thetaT = (unsigned short*)d_ws;      // 8*4096*128 bf16 = 8 MB
    unsigned short* phiPt  = thetaT + (size_t)4194304;   // 8*1024*128 bf16 = 2 MB
    unsigned short* gPc    = phiPt + (size_t)1048576;    // 2 MB
    float*          y      = (float*)(gPc + (size_t)1048576);  // 8*4096*128 f32 = 16 MB

    k_conv3<<<dim3(Bn * 64), dim3(256), 0, stream>>>(
        x, g_w, g_b, th_w, th_b, ph_w, ph_b, thetaT, gPc, phiPt);
    k_attn<<<dim3(Bn * 64), dim3(256), 0, stream>>>(thetaT, phiPt, gPc, y);
    k_out<<<dim3(Bn * 64), dim3(256), 0, stream>>>(
        y, x, W_w, W_b, gmm, bta, mmn, vvr, out);
}

// Round 4
// 273.925 us; speedup vs baseline: 2.7905x; 1.4448x over previous
//
#include <hip/hip_runtime.h>
#include <math.h>

// Problem constants
#define Bn   8
#define Cc   256     // input channels
#define Cin  128     // inter channels
#define Hh   64
#define Ww   64
#define Nn   4096    // H*W
#define Npl  1024    // pooled pixels (32*32)
#define EPSf 1e-5f

typedef __attribute__((ext_vector_type(8))) short short8;    // 8 bf16 (4 VGPRs)
typedef __attribute__((ext_vector_type(4))) float floatx4;   // MFMA C/D

__device__ __forceinline__ unsigned short f2bf(float f) {
    unsigned int u = __float_as_uint(f);
    u += 0x7fffu + ((u >> 16) & 1u);     // round-to-nearest-even
    return (unsigned short)(u >> 16);
}

// ---------------------------------------------------------------------------
// Kernel 0: fold BN scale into W (bf16) and precompute the additive vector.
//   Wbf[o][c] = bf16(W_w[o][c] * inv[o]),  inv = gamma/sqrt(var+eps)
//   cvec[o]   = (W_b[o]-mean[o])*inv[o] + beta[o]
// ---------------------------------------------------------------------------
__global__ __launch_bounds__(256) void k_prep(
    const float* __restrict__ W_w, const float* __restrict__ W_b,
    const float* __restrict__ gamma, const float* __restrict__ beta,
    const float* __restrict__ mean,  const float* __restrict__ var,
    unsigned short* __restrict__ Wbf, float* __restrict__ cvec)
{
    int i = blockIdx.x * 256 + threadIdx.x;     // grid 128 -> 32768
    int o = i >> 7;
    float inv = gamma[o] * rsqrtf(var[o] + EPSf);
    Wbf[i] = f2bf(W_w[i] * inv);
    if (i < Cc) {
        float invi = gamma[i] * rsqrtf(var[i] + EPSf);
        cvec[i] = (W_b[i] - mean[i]) * invi + beta[i];
    }
}

// ---------------------------------------------------------------------------
// Kernel 1: fused conv1x1 for g/theta/phi (+ bias) with 2x2 maxpool on g,phi.
// fp32 compute (VALU), bf16 outputs in MFMA-friendly layouts:
//   thetaT: [B, 4096, 128] bf16 (pixel-major -> Q rows)
//   phiPt:  [B, 1024, 128] bf16 (pixel-major -> K rows)
//   gPc:    [B, 128, 1024] bf16 (channel-major -> V^T staging)
// ---------------------------------------------------------------------------
__global__ __launch_bounds__(256) void k_conv3(
    const float* __restrict__ x,
    const float* __restrict__ g_w,  const float* __restrict__ g_b,
    const float* __restrict__ th_w, const float* __restrict__ th_b,
    const float* __restrict__ ph_w, const float* __restrict__ ph_b,
    unsigned short* __restrict__ thetaT,
    unsigned short* __restrict__ gPc,
    unsigned short* __restrict__ phiPt)
{
    __shared__ float xs[Cc * 64];            // [c][p], 64 KB
    const int t    = threadIdx.x;
    const int b    = blockIdx.x >> 6;        // 64 tiles per batch
    const int tile = blockIdx.x & 63;
    const int ty   = tile >> 1;              // 0..31 (pair of full-res rows)
    const int tx   = tile & 1;               // 0..1  (32-col half)
    const int n_base = ty * 2 * Ww + tx * 32;

    // stage x tile: float4 over pixels
    {
        const float4* xg  = (const float4*)x;
        float4*       xs4 = (float4*)xs;
        #pragma unroll
        for (int it = 0; it < 16; ++it) {
            int idx  = t + 256 * it;          // 0..4095 float4 units
            int c    = idx >> 4;              // 0..255
            int p4   = idx & 15;              // pixel quad
            int prow = p4 >> 3;               // 0/1
            int pc4  = p4 & 7;                // col quad within row
            int gidx = ((b * Cc + c) * Nn + n_base + prow * Ww) / 4 + pc4;
            xs4[c * 16 + p4] = xg[gidx];
        }
    }
    __syncthreads();

    const int pg   = t & 15;                 // pixel quad id: pixels pg*4..pg*4+3
    const int og   = t >> 4;                 // 0..15, 24 output channels each
    const int p0   = pg * 4;
    const int prow = p0 >> 5;
    const int pcol = p0 & 31;
    const int n0   = n_base + prow * Ww + pcol;   // 4 consecutive n
    const int np0  = ty * 32 + tx * 16 + pg * 2;  // pooled (valid if pg<8)

    const float4* xs4 = (const float4*)xs;

    for (int ob = 0; ob < 6; ++ob) {
        int o    = og * 24 + ob * 4;          // 4 channels, 4-aligned -> one segment
        int seg  = o >> 7;                    // 0:g  1:theta  2:phi
        int wrow = o - (seg << 7);
        const float4* wb = (const float4*)(seg == 0 ? g_w : (seg == 1 ? th_w : ph_w));
        const float*  bb = (seg == 0 ? g_b : (seg == 1 ? th_b : ph_b));

        float acc[4][4] = {};
        for (int c4 = 0; c4 < 64; ++c4) {
            float4 xa = xs4[(c4 * 4 + 0) * 16 + pg];
            float4 xb = xs4[(c4 * 4 + 1) * 16 + pg];
            float4 xc = xs4[(c4 * 4 + 2) * 16 + pg];
            float4 xd = xs4[(c4 * 4 + 3) * 16 + pg];
            #pragma unroll
            for (int i = 0; i < 4; ++i) {
                float4 wv = wb[(wrow + i) * 64 + c4];
                acc[i][0] += wv.x * xa.x + wv.y * xb.x + wv.z * xc.x + wv.w * xd.x;
                acc[i][1] += wv.x * xa.y + wv.y * xb.y + wv.z * xc.y + wv.w * xd.y;
                acc[i][2] += wv.x * xa.z + wv.y * xb.z + wv.z * xc.z + wv.w * xd.z;
                acc[i][3] += wv.x * xa.w + wv.y * xb.w + wv.z * xc.w + wv.w * xd.w;
            }
        }

        if (seg == 1) {                        // theta -> thetaT [B,N,128] bf16
            float b0 = bb[wrow], b1 = bb[wrow + 1], b2 = bb[wrow + 2], b3 = bb[wrow + 3];
            #pragma unroll
            for (int j = 0; j < 4; ++j) {
                ushort4 v;
                v.x = f2bf(acc[0][j] + b0);
                v.y = f2bf(acc[1][j] + b1);
                v.z = f2bf(acc[2][j] + b2);
                v.w = f2bf(acc[3][j] + b3);
                *(ushort4*)&thetaT[((size_t)b * Nn + n0 + j) * Cin + wrow] = v;
            }
        } else {                               // g / phi: 2x2 maxpool then store bf16
            float v0[4], v1[4];
            #pragma unroll
            for (int i = 0; i < 4; ++i) {
                float bias = bb[wrow + i];
                float m01 = fmaxf(acc[i][0], acc[i][1]);
                float m23 = fmaxf(acc[i][2], acc[i][3]);
                v0[i] = fmaxf(m01, __shfl_xor(m01, 8, 64)) + bias;  // pooled pixel np0
                v1[i] = fmaxf(m23, __shfl_xor(m23, 8, 64)) + bias;  // pooled pixel np0+1
            }
            if (pg < 8) {
                if (seg == 0) {                // g -> gPc [B,128,1024] channel-major
                    #pragma unroll
                    for (int i = 0; i < 4; ++i) {
                        ushort2 vv;
                        vv.x = f2bf(v0[i]); vv.y = f2bf(v1[i]);
                        *(ushort2*)&gPc[((size_t)b * Cin + wrow + i) * Npl + np0] = vv;
                    }
                } else {                       // phi -> phiPt [B,1024,128] pixel-major
                    ushort4 a, c;
                    a.x = f2bf(v0[0]); a.y = f2bf(v0[1]); a.z = f2bf(v0[2]); a.w = f2bf(v0[3]);
                    c.x = f2bf(v1[0]); c.y = f2bf(v1[1]); c.z = f2bf(v1[2]); c.w = f2bf(v1[3]);
                    *(ushort4*)&phiPt[((size_t)b * Npl + np0) * Cin + wrow] = a;
                    *(ushort4*)&phiPt[((size_t)b * Npl + np0 + 1) * Cin + wrow] = c;
                }
            }
        }
    }
}

// ---------------------------------------------------------------------------
// Kernel 2: flash attention, bf16 MFMA (16x16x32), online softmax in registers.
//   Q = thetaT [B,N,128], K = phiPt [B,Np,128], V^T = gPc [B,128,Np]
//   yb [B, N, 128] bf16 (pixel-major for kernel 3)
// MFMA frag mapping: A[m=lane&15][k=quad*8+j], B[n=lane&15][k=quad*8+j],
//                    D[row=quad*4+r][col=lane&15]
// ---------------------------------------------------------------------------
#define DPAD 136
#define VPAD 72
#define PPAD 72

__global__ __launch_bounds__(256) void k_attn(
    const unsigned short* __restrict__ thetaT,
    const unsigned short* __restrict__ phiPt,
    const unsigned short* __restrict__ gPc,
    unsigned short* __restrict__ yb)
{
    __shared__ __align__(16) unsigned short Qs[64 * DPAD];     // 17.0 KB
    __shared__ __align__(16) unsigned short Ks[64 * DPAD];     // 17.0 KB
    __shared__ __align__(16) unsigned short Vt[Cin * VPAD];    // 18.0 KB
    __shared__ __align__(16) unsigned short Ps[4][16 * PPAD];  // 9.0 KB (per-wave)

    const int t    = threadIdx.x;
    const int w    = t >> 6;        // wave id: q rows w*16..w*16+15
    const int l    = t & 63;
    const int quad = l >> 4;
    const int l16  = l & 15;
    const int b    = blockIdx.x >> 6;
    const int qb   = blockIdx.x & 63;
    const int n0   = qb * 64;

    // stage Q tile (64 rows x 128 bf16): 4 iters x 2048 bf16
    #pragma unroll
    for (int it = 0; it < 4; ++it) {
        int idx = t + 256 * it;          // 0..1023
        int q = idx >> 4, d8 = idx & 15;
        *(uint4*)&Qs[q * DPAD + d8 * 8] =
            *(const uint4*)&thetaT[((size_t)b * Nn + n0 + q) * Cin + d8 * 8];
    }
    __syncthreads();

    // Q A-fragments (chunk-invariant)
    short8 qf[4];
    #pragma unroll
    for (int kd = 0; kd < 4; ++kd)
        qf[kd] = *(const short8*)&Qs[(w * 16 + l16) * DPAD + kd * 32 + quad * 8];

    floatx4 yacc[8] = {};                     // Y[16 q x 128 c] per wave
    float mi[4] = {-1e30f, -1e30f, -1e30f, -1e30f};
    float li[4] = {0.f, 0.f, 0.f, 0.f};

    for (int ch = 0; ch < 16; ++ch) {
        __syncthreads();                      // prior chunk's K/V frag reads done
        // stage K chunk: [64 m x 128 d] bf16
        #pragma unroll
        for (int it = 0; it < 4; ++it) {
            int idx = t + 256 * it;          // 0..1023
            int m = idx >> 4, d8 = idx & 15;
            *(uint4*)&Ks[m * DPAD + d8 * 8] =
                *(const uint4*)&phiPt[((size_t)b * Npl + ch * 64 + m) * Cin + d8 * 8];
        }
        // stage V^T chunk: Vt[c][m] (128 c x 64 m), from channel-major gPc
        #pragma unroll
        for (int it = 0; it < 4; ++it) {
            int idx = t + 256 * it;          // 0..1023
            int c = idx >> 3, m8 = idx & 7;
            *(uint4*)&Vt[c * VPAD + m8 * 8] =
                *(const uint4*)&gPc[((size_t)b * Cin + c) * Npl + ch * 64 + m8 * 8];
        }
        __syncthreads();

        // S[16 q x 64 m] = Q K^T : 4 m-tiles x 4 k-depth MFMAs
        floatx4 sacc[4] = {};
        #pragma unroll
        for (int mt = 0; mt < 4; ++mt) {
            #pragma unroll
            for (int kd = 0; kd < 4; ++kd) {
                short8 kf = *(const short8*)&Ks[(mt * 16 + l16) * DPAD + kd * 32 + quad * 8];
                sacc[mt] = __builtin_amdgcn_mfma_f32_16x16x32_bf16(qf[kd], kf, sacc[mt], 0, 0, 0);
            }
        }

        // online softmax: row q = quad*4+r lives on 16 lanes (fixed quad), reg r
        float mnew[4];
        int anyup = 0;
        #pragma unroll
        for (int r = 0; r < 4; ++r) {
            float mx = fmaxf(fmaxf(sacc[0][r], sacc[1][r]), fmaxf(sacc[2][r], sacc[3][r]));
            #pragma unroll
            for (int o = 1; o < 16; o <<= 1) mx = fmaxf(mx, __shfl_xor(mx, o, 64));
            mnew[r] = fmaxf(mi[r], mx);
            anyup |= (mnew[r] > mi[r]) ? 1 : 0;
        }
        if (__any(anyup)) {                   // wave-uniform rescale (rare after warmup)
            #pragma unroll
            for (int r = 0; r < 4; ++r) {
                float alpha = __expf(mi[r] - mnew[r]);
                li[r] *= alpha;
                #pragma unroll
                for (int ct = 0; ct < 8; ++ct) yacc[ct][r] *= alpha;
            }
        }
        float pv[4][4];                       // [mt][r]
        #pragma unroll
        for (int r = 0; r < 4; ++r) {
            mi[r] = mnew[r];
            float rs = 0.f;
            #pragma unroll
            for (int mt = 0; mt < 4; ++mt) {
                float e = __expf(sacc[mt][r] - mnew[r]);
                pv[mt][r] = e; rs += e;
            }
            #pragma unroll
            for (int o = 1; o < 16; o <<= 1) rs += __shfl_xor(rs, o, 64);
            li[r] += rs;
        }

        // P: C/D layout -> LDS (per-wave) -> A layout
        #pragma unroll
        for (int mt = 0; mt < 4; ++mt)
            #pragma unroll
            for (int r = 0; r < 4; ++r)
                Ps[w][(quad * 4 + r) * PPAD + mt * 16 + l16] = f2bf(pv[mt][r]);

        short8 pf[2];
        #pragma unroll
        for (int kd = 0; kd < 2; ++kd)
            pf[kd] = *(const short8*)&Ps[w][l16 * PPAD + kd * 32 + quad * 8];

        // Y += P V : 8 c-tiles x 2 k-depth MFMAs
        #pragma unroll
        for (int ct = 0; ct < 8; ++ct) {
            #pragma unroll
            for (int kd = 0; kd < 2; ++kd) {
                short8 vf = *(const short8*)&Vt[(ct * 16 + l16) * VPAD + kd * 32 + quad * 8];
                yacc[ct] = __builtin_amdgcn_mfma_f32_16x16x32_bf16(pf[kd], vf, yacc[ct], 0, 0, 0);
            }
        }
    }

    // normalize and store y [B,N,128] bf16
    #pragma unroll
    for (int r = 0; r < 4; ++r) {
        float il = 1.0f / li[r];
        int q = n0 + w * 16 + quad * 4 + r;
        unsigned short* yr = yb + ((size_t)b * Nn + q) * Cin;
        #pragma unroll
        for (int ct = 0; ct < 8; ++ct)
            yr[ct * 16 + l16] = f2bf(yacc[ct][r] * il);
    }
}

// ---------------------------------------------------------------------------
// Kernel 3: out = Wbf @ y + cvec + x   (BN pre-folded into Wbf/cvec)
//   yb [B,N,128] bf16, Wbf [256,128] bf16, out/x [B,256,4096] fp32
// Block: 64 pixels x all 256 o. A = W' (m=o), B = y^T (n=q) -> D cols are 16
// consecutive pixels -> coalesced 64 B stores. 2 o-chunks of 128 (LDS 52 KB).
// ---------------------------------------------------------------------------
__global__ __launch_bounds__(256) void k_out(
    const unsigned short* __restrict__ yb, const float* __restrict__ x,
    const unsigned short* __restrict__ Wbf, const float* __restrict__ cvec,
    float* __restrict__ out)
{
    __shared__ __align__(16) unsigned short Ys[64 * DPAD];    // 17.4 KB
    __shared__ __align__(16) unsigned short Ws[128 * DPAD];   // 34.8 KB

    const int t    = threadIdx.x;
    const int w    = t >> 6;
    const int l    = t & 63;
    const int quad = l >> 4;
    const int l16  = l & 15;
    const int b    = blockIdx.x >> 6;
    const int qt   = blockIdx.x & 63;
    const int n0   = qt * 64;

    // stage y tile [64 q x 128 c]
    #pragma unroll
    for (int it = 0; it < 4; ++it) {
        int idx = t + 256 * it;              // 0..1023
        int q = idx >> 4, d8 = idx & 15;
        *(uint4*)&Ys[q * DPAD + d8 * 8] =
            *(const uint4*)&yb[((size_t)b * Nn + n0 + q) * Cin + d8 * 8];
    }

    for (int oc = 0; oc < 2; ++oc) {
        __syncthreads();                      // Ws reuse + (first iter) Ys ready-gate
        // stage W chunk [128 o x 128 c]
        #pragma unroll
        for (int it = 0; it < 8; ++it) {
            int idx = t + 256 * it;          // 0..2047
            int o = idx >> 4, d8 = idx & 15;
            *(uint4*)&Ws[o * DPAD + d8 * 8] =
                *(const uint4*)&Wbf[((size_t)(oc * 128 + o)) * Cin + d8 * 8];
        }
        __syncthreads();

        // A-frags: W rows (m = o), 2 m-tiles per wave
        short8 af[2][4];
        #pragma unroll
        for (int mt = 0; mt < 2; ++mt)
            #pragma unroll
            for (int kd = 0; kd < 4; ++kd)
                af[mt][kd] = *(const short8*)&Ws[(w * 32 + mt * 16 + l16) * DPAD + kd * 32 + quad * 8];

        floatx4 acc[2][4] = {};
        #pragma unroll
        for (int nt = 0; nt < 4; ++nt) {
            short8 bfr[4];
            #pragma unroll
            for (int kd = 0; kd < 4; ++kd)
                bfr[kd] = *(const short8*)&Ys[(nt * 16 + l16) * DPAD + kd * 32 + quad * 8];
            #pragma unroll
            for (int mt = 0; mt < 2; ++mt)
                #pragma unroll
                for (int kd = 0; kd < 4; ++kd)
                    acc[mt][nt] = __builtin_amdgcn_mfma_f32_16x16x32_bf16(af[mt][kd], bfr[kd], acc[mt][nt], 0, 0, 0);
        }

        // epilogue: out = D + cvec[o] + x, coalesced 16-lane 64 B segments
        #pragma unroll
        for (int mt = 0; mt < 2; ++mt) {
            #pragma unroll
            for (int r = 0; r < 4; ++r) {
                int o = oc * 128 + w * 32 + mt * 16 + quad * 4 + r;
                float cv = cvec[o];
                #pragma unroll
                for (int nt = 0; nt < 4; ++nt) {
                    size_t gi = ((size_t)(b * Cc + o)) * Nn + n0 + nt * 16 + l16;
                    out[gi] = acc[mt][nt][r] + cv + x[gi];
                }
            }
        }
    }
}

// ---------------------------------------------------------------------------
extern "C" void kernel_launch(void* const* d_in, const int* in_sizes, int n_in,
                              void* d_out, int out_size, void* d_ws, size_t ws_size,
                              hipStream_t stream) {
    const float* x    = (const float*)d_in[0];
    const float* g_w  = (const float*)d_in[1];
    const float* g_b  = (const float*)d_in[2];
    const float* th_w = (const float*)d_in[3];
    const float* th_b = (const float*)d_in[4];
    const float* ph_w = (const float*)d_in[5];
    const float* ph_b = (const float*)d_in[6];
    const float* W_w  = (const float*)d_in[7];
    const float* W_b  = (const float*)d_in[8];
    const float* gmm  = (const float*)d_in[9];
    const float* bta  = (const float*)d_in[10];
    const float* mmn  = (const float*)d_in[11];
    const float* vvr  = (const float*)d_in[12];
    float* out = (float*)d_out;

    unsigned short* thetaT = (unsigned short*)d_ws;      // 8 MB
    unsigned short* phiPt  = thetaT + (size_t)4194304;   // 2 MB
    unsigned short* gPc    = phiPt + (size_t)1048576;    // 2 MB
    unsigned short* yb     = gPc + (size_t)1048576;      // 8 MB
    unsigned short* Wbf    = yb + (size_t)4194304;       // 64 KB
    float*          cvec   = (float*)(Wbf + 32768);      // 1 KB

    k_prep<<<dim3(128), dim3(256), 0, stream>>>(W_w, W_b, gmm, bta, mmn, vvr, Wbf, cvec);
    k_conv3<<<dim3(Bn * 64), dim3(256), 0, stream>>>(
        x, g_w, g_b, th_w, th_b, ph_w, ph_b, thetaT, gPc, phiPt);
    k_attn<<<dim3(Bn * 64), dim3(256), 0, stream>>>(thetaT, phiPt, gPc, yb);
    k_out<<<dim3(Bn * 64), dim3(256), 0, stream>>>(yb, x, Wbf, cvec, out);
}

// Round 5
// 190.662 us; speedup vs baseline: 4.0091x; 1.4367x over previous
//
#include <hip/hip_runtime.h>
#include <math.h>

// Problem constants
#define Bn   8
#define Cc   256     // input channels
#define Cin  128     // inter channels
#define Hh   64
#define Ww   64
#define Nn   4096    // H*W
#define Npl  1024    // pooled pixels (32*32)
#define EPSf 1e-5f

typedef __attribute__((ext_vector_type(8))) short short8;    // 8 bf16 (4 VGPRs)
typedef __attribute__((ext_vector_type(4))) float floatx4;   // MFMA C/D

__device__ __forceinline__ unsigned short f2bf(float f) {
    unsigned int u = __float_as_uint(f);
    u += 0x7fffu + ((u >> 16) & 1u);     // round-to-nearest-even
    return (unsigned short)(u >> 16);
}
__device__ __forceinline__ float bf2f(unsigned short h) {
    return __uint_as_float(((unsigned int)h) << 16);
}

// ---------------------------------------------------------------------------
// Kernel 0 (prep):
//  - split g/theta/phi conv weights into bf16 hi (+ lo for theta/phi)
//  - fold BN into W (bf16) and the additive vector cvec
// grid 512 x 256: i<98304 -> conv weights (seg=i>>15), else Wbf fold.
// ---------------------------------------------------------------------------
__global__ __launch_bounds__(256) void k_prep(
    const float* __restrict__ g_w, const float* __restrict__ th_w,
    const float* __restrict__ ph_w,
    const float* __restrict__ W_w, const float* __restrict__ W_b,
    const float* __restrict__ gamma, const float* __restrict__ beta,
    const float* __restrict__ mean,  const float* __restrict__ var,
    unsigned short* __restrict__ gWh,
    unsigned short* __restrict__ thWh, unsigned short* __restrict__ thWl,
    unsigned short* __restrict__ phWh, unsigned short* __restrict__ phWl,
    unsigned short* __restrict__ Wbf, float* __restrict__ cvec)
{
    int i = blockIdx.x * 256 + threadIdx.x;
    if (i < 98304) {                          // 3 x 128 x 256 conv weights
        int seg = i >> 15;                    // 0:g 1:theta 2:phi
        int idx = i & 32767;
        float v = (seg == 0 ? g_w : (seg == 1 ? th_w : ph_w))[idx];
        unsigned short hi = f2bf(v);
        if (seg == 0) gWh[idx] = hi;
        else {
            (seg == 1 ? thWh : phWh)[idx] = hi;
            (seg == 1 ? thWl : phWl)[idx] = f2bf(v - bf2f(hi));
        }
    } else {
        int j = i - 98304;                    // 0..32767 : Wbf fold (256x128)
        int o = j >> 7;
        float inv = gamma[o] * rsqrtf(var[o] + EPSf);
        Wbf[j] = f2bf(W_w[j] * inv);
        if (j < Cc) {
            float invi = gamma[j] * rsqrtf(var[j] + EPSf);
            cvec[j] = (W_b[j] - mean[j]) * invi + beta[j];
        }
    }
}

// ---------------------------------------------------------------------------
// Kernel 1: fused conv1x1 g/theta/phi via bf16 MFMA, split-precision on
// theta/phi (hi*hi + hi*lo + lo*hi ~= fp32), single bf16 pass for g.
// Tile: 2 rows x 32 cols (64 px) x all 384 outputs. X staged transposed
// [px][c] as hi/lo bf16. W frags from global (L1/L2 resident).
// Pool 2x2: nt-pair (rows) + shfl_xor(.,1) (cols).
//   thetaT: [B,4096,128] bf16   phiPt: [B,1024,128] bf16   gPc: [B,128,1024]
// ---------------------------------------------------------------------------
#define XPAD 264   // bf16 per px row (256 + 8) -> 132 dwords

__global__ __launch_bounds__(256, 2) void k_conv3(
    const float* __restrict__ x,
    const unsigned short* __restrict__ gWh,
    const unsigned short* __restrict__ thWh, const unsigned short* __restrict__ thWl,
    const unsigned short* __restrict__ phWh, const unsigned short* __restrict__ phWl,
    const float* __restrict__ g_b, const float* __restrict__ th_b,
    const float* __restrict__ ph_b,
    unsigned short* __restrict__ thetaT,
    unsigned short* __restrict__ gPc,
    unsigned short* __restrict__ phiPt)
{
    __shared__ __align__(16) unsigned short Xhi[64 * XPAD];   // 33 KB
    __shared__ __align__(16) unsigned short Xlo[64 * XPAD];   // 33 KB

    const int t    = threadIdx.x;
    const int w    = t >> 6;
    const int l    = t & 63;
    const int quad = l >> 4;
    const int l16  = l & 15;
    const int b    = blockIdx.x >> 6;
    const int tile = blockIdx.x & 63;
    const int ty   = tile >> 1;              // image rows 2ty, 2ty+1
    const int tx   = tile & 1;               // 32-col half

    // stage x tile transposed + hi/lo split: 2048 (c-pair, px-quad) units
    {
        const float4* xg = (const float4*)x;
        unsigned int* XhiW = (unsigned int*)Xhi;
        unsigned int* XloW = (unsigned int*)Xlo;
        #pragma unroll
        for (int it = 0; it < 8; ++it) {
            int idx = t + 256 * it;          // 0..2047
            int c2  = idx >> 4;              // channel pair 0..127
            int p4  = idx & 15;              // px quad 0..15
            int n   = (2 * ty + (p4 >> 3)) * Ww + tx * 32 + (p4 & 7) * 4;
            float4 va = xg[((size_t)(b * Cc + 2 * c2) * Nn + n) >> 2];
            float4 vb = xg[((size_t)(b * Cc + 2 * c2 + 1) * Nn + n) >> 2];
            const float fa[4] = {va.x, va.y, va.z, va.w};
            const float fb[4] = {vb.x, vb.y, vb.z, vb.w};
            #pragma unroll
            for (int i = 0; i < 4; ++i) {
                int px = p4 * 4 + i;
                unsigned short ha = f2bf(fa[i]), hb = f2bf(fb[i]);
                unsigned short la = f2bf(fa[i] - bf2f(ha));
                unsigned short lb = f2bf(fb[i] - bf2f(hb));
                XhiW[px * 132 + c2] = (unsigned int)ha | ((unsigned int)hb << 16);
                XloW[px * 132 + c2] = (unsigned int)la | ((unsigned int)lb << 16);
            }
        }
    }
    __syncthreads();

    // wave w owns o-tiles {w, w+4, ..., w+20}; seg = ot>>3 (0:g 1:th 2:ph)
    floatx4 acc[6][4] = {};

    #pragma unroll 2
    for (int kd = 0; kd < 8; ++kd) {
        short8 bhi[4], blo[4];
        #pragma unroll
        for (int nt = 0; nt < 4; ++nt) {
            bhi[nt] = *(const short8*)&Xhi[(nt * 16 + l16) * XPAD + kd * 32 + quad * 8];
            blo[nt] = *(const short8*)&Xlo[(nt * 16 + l16) * XPAD + kd * 32 + quad * 8];
        }
        #pragma unroll
        for (int ti = 0; ti < 6; ++ti) {
            int ot  = w + 4 * ti;
            int seg = ot >> 3;
            size_t aoff = (size_t)((ot & 7) * 16 + l16) * Cc + kd * 32 + quad * 8;
            const unsigned short* wh = (seg == 0 ? gWh : (seg == 1 ? thWh : phWh));
            short8 ah = *(const short8*)&wh[aoff];
            #pragma unroll
            for (int nt = 0; nt < 4; ++nt)
                acc[ti][nt] = __builtin_amdgcn_mfma_f32_16x16x32_bf16(ah, bhi[nt], acc[ti][nt], 0, 0, 0);
            if (seg != 0) {
                const unsigned short* wl = (seg == 1 ? thWl : phWl);
                short8 al = *(const short8*)&wl[aoff];
                #pragma unroll
                for (int nt = 0; nt < 4; ++nt) {
                    acc[ti][nt] = __builtin_amdgcn_mfma_f32_16x16x32_bf16(ah, blo[nt], acc[ti][nt], 0, 0, 0);
                    acc[ti][nt] = __builtin_amdgcn_mfma_f32_16x16x32_bf16(al, bhi[nt], acc[ti][nt], 0, 0, 0);
                }
            }
        }
    }

    // epilogue: D[row=quad*4+r][col=l16]
    #pragma unroll
    for (int ti = 0; ti < 6; ++ti) {
        int ot  = w + 4 * ti;
        int seg = ot >> 3;
        int ol  = (ot & 7) * 16 + quad * 4;       // seg-local o for r=0..3
        if (seg == 1) {                            // theta: full-res, [n][o]
            float b0 = th_b[ol], b1 = th_b[ol + 1], b2 = th_b[ol + 2], b3 = th_b[ol + 3];
            #pragma unroll
            for (int nt = 0; nt < 4; ++nt) {
                int n = (2 * ty + (nt >> 1)) * Ww + tx * 32 + (nt & 1) * 16 + l16;
                ushort4 v;
                v.x = f2bf(acc[ti][nt][0] + b0);
                v.y = f2bf(acc[ti][nt][1] + b1);
                v.z = f2bf(acc[ti][nt][2] + b2);
                v.w = f2bf(acc[ti][nt][3] + b3);
                *(ushort4*)&thetaT[((size_t)b * Nn + n) * Cin + ol] = v;
            }
        } else {                                   // g / phi: 2x2 maxpool
            const float* bb = (seg == 0 ? g_b : ph_b);
            float b0 = bb[ol], b1 = bb[ol + 1], b2 = bb[ol + 2], b3 = bb[ol + 3];
            #pragma unroll
            for (int pp = 0; pp < 2; ++pp) {       // nt pair (pp, pp+2) = row pair
                float pm[4];
                #pragma unroll
                for (int r = 0; r < 4; ++r) {
                    float m = fmaxf(acc[ti][pp][r], acc[ti][pp + 2][r]);
                    pm[r] = fmaxf(m, __shfl_xor(m, 1, 64));   // col pair
                }
                int np = ty * 32 + tx * 16 + pp * 8 + (l16 >> 1);
                if ((l16 & 1) == 0) {
                    if (seg == 0) {                // g -> [o][np] channel-major
                        gPc[((size_t)b * Cin + ol + 0) * Npl + np] = f2bf(pm[0] + b0);
                        gPc[((size_t)b * Cin + ol + 1) * Npl + np] = f2bf(pm[1] + b1);
                        gPc[((size_t)b * Cin + ol + 2) * Npl + np] = f2bf(pm[2] + b2);
                        gPc[((size_t)b * Cin + ol + 3) * Npl + np] = f2bf(pm[3] + b3);
                    } else {                       // phi -> [np][o] pixel-major
                        ushort4 v;
                        v.x = f2bf(pm[0] + b0); v.y = f2bf(pm[1] + b1);
                        v.z = f2bf(pm[2] + b2); v.w = f2bf(pm[3] + b3);
                        *(ushort4*)&phiPt[((size_t)b * Npl + np) * Cin + ol] = v;
                    }
                }
            }
        }
    }
}

// ---------------------------------------------------------------------------
// Kernel 2: flash attention, bf16 MFMA (16x16x32), online softmax in registers.
//   Q = thetaT [B,N,128], K = phiPt [B,Np,128], V^T = gPc [B,128,Np]
//   yb [B, N, 128] bf16 (pixel-major for kernel 3)
// MFMA frag mapping: A[m=lane&15][k=quad*8+j], B[n=lane&15][k=quad*8+j],
//                    D[row=quad*4+r][col=lane&15]
// ---------------------------------------------------------------------------
#define DPAD 136
#define VPAD 72
#define PPAD 72

__global__ __launch_bounds__(256) void k_attn(
    const unsigned short* __restrict__ thetaT,
    const unsigned short* __restrict__ phiPt,
    const unsigned short* __restrict__ gPc,
    unsigned short* __restrict__ yb)
{
    __shared__ __align__(16) unsigned short Qs[64 * DPAD];     // 17.0 KB
    __shared__ __align__(16) unsigned short Ks[64 * DPAD];     // 17.0 KB
    __shared__ __align__(16) unsigned short Vt[Cin * VPAD];    // 18.0 KB
    __shared__ __align__(16) unsigned short Ps[4][16 * PPAD];  // 9.0 KB (per-wave)

    const int t    = threadIdx.x;
    const int w    = t >> 6;        // wave id: q rows w*16..w*16+15
    const int l    = t & 63;
    const int quad = l >> 4;
    const int l16  = l & 15;
    const int b    = blockIdx.x >> 6;
    const int qb   = blockIdx.x & 63;
    const int n0   = qb * 64;

    // stage Q tile (64 rows x 128 bf16): 4 iters x 2048 bf16
    #pragma unroll
    for (int it = 0; it < 4; ++it) {
        int idx = t + 256 * it;          // 0..1023
        int q = idx >> 4, d8 = idx & 15;
        *(uint4*)&Qs[q * DPAD + d8 * 8] =
            *(const uint4*)&thetaT[((size_t)b * Nn + n0 + q) * Cin + d8 * 8];
    }
    __syncthreads();

    // Q A-fragments (chunk-invariant)
    short8 qf[4];
    #pragma unroll
    for (int kd = 0; kd < 4; ++kd)
        qf[kd] = *(const short8*)&Qs[(w * 16 + l16) * DPAD + kd * 32 + quad * 8];

    floatx4 yacc[8] = {};                     // Y[16 q x 128 c] per wave
    float mi[4] = {-1e30f, -1e30f, -1e30f, -1e30f};
    float li[4] = {0.f, 0.f, 0.f, 0.f};

    for (int ch = 0; ch < 16; ++ch) {
        __syncthreads();                      // prior chunk's K/V frag reads done
        // stage K chunk: [64 m x 128 d] bf16
        #pragma unroll
        for (int it = 0; it < 4; ++it) {
            int idx = t + 256 * it;          // 0..1023
            int m = idx >> 4, d8 = idx & 15;
            *(uint4*)&Ks[m * DPAD + d8 * 8] =
                *(const uint4*)&phiPt[((size_t)b * Npl + ch * 64 + m) * Cin + d8 * 8];
        }
        // stage V^T chunk: Vt[c][m] (128 c x 64 m), from channel-major gPc
        #pragma unroll
        for (int it = 0; it < 4; ++it) {
            int idx = t + 256 * it;          // 0..1023
            int c = idx >> 3, m8 = idx & 7;
            *(uint4*)&Vt[c * VPAD + m8 * 8] =
                *(const uint4*)&gPc[((size_t)b * Cin + c) * Npl + ch * 64 + m8 * 8];
        }
        __syncthreads();

        // S[16 q x 64 m] = Q K^T : 4 m-tiles x 4 k-depth MFMAs
        floatx4 sacc[4] = {};
        #pragma unroll
        for (int mt = 0; mt < 4; ++mt) {
            #pragma unroll
            for (int kd = 0; kd < 4; ++kd) {
                short8 kf = *(const short8*)&Ks[(mt * 16 + l16) * DPAD + kd * 32 + quad * 8];
                sacc[mt] = __builtin_amdgcn_mfma_f32_16x16x32_bf16(qf[kd], kf, sacc[mt], 0, 0, 0);
            }
        }

        // online softmax: row q = quad*4+r lives on 16 lanes (fixed quad), reg r
        float mnew[4];
        int anyup = 0;
        #pragma unroll
        for (int r = 0; r < 4; ++r) {
            float mx = fmaxf(fmaxf(sacc[0][r], sacc[1][r]), fmaxf(sacc[2][r], sacc[3][r]));
            #pragma unroll
            for (int o = 1; o < 16; o <<= 1) mx = fmaxf(mx, __shfl_xor(mx, o, 64));
            mnew[r] = fmaxf(mi[r], mx);
            anyup |= (mnew[r] > mi[r]) ? 1 : 0;
        }
        if (__any(anyup)) {                   // wave-uniform rescale
            #pragma unroll
            for (int r = 0; r < 4; ++r) {
                float alpha = __expf(mi[r] - mnew[r]);
                li[r] *= alpha;
                #pragma unroll
                for (int ct = 0; ct < 8; ++ct) yacc[ct][r] *= alpha;
            }
        }
        float pv[4][4];                       // [mt][r]
        #pragma unroll
        for (int r = 0; r < 4; ++r) {
            mi[r] = mnew[r];
            float rs = 0.f;
            #pragma unroll
            for (int mt = 0; mt < 4; ++mt) {
                float e = __expf(sacc[mt][r] - mnew[r]);
                pv[mt][r] = e; rs += e;
            }
            #pragma unroll
            for (int o = 1; o < 16; o <<= 1) rs += __shfl_xor(rs, o, 64);
            li[r] += rs;
        }

        // P: C/D layout -> LDS (per-wave) -> A layout
        #pragma unroll
        for (int mt = 0; mt < 4; ++mt)
            #pragma unroll
            for (int r = 0; r < 4; ++r)
                Ps[w][(quad * 4 + r) * PPAD + mt * 16 + l16] = f2bf(pv[mt][r]);

        short8 pf[2];
        #pragma unroll
        for (int kd = 0; kd < 2; ++kd)
            pf[kd] = *(const short8*)&Ps[w][l16 * PPAD + kd * 32 + quad * 8];

        // Y += P V : 8 c-tiles x 2 k-depth MFMAs
        #pragma unroll
        for (int ct = 0; ct < 8; ++ct) {
            #pragma unroll
            for (int kd = 0; kd < 2; ++kd) {
                short8 vf = *(const short8*)&Vt[(ct * 16 + l16) * VPAD + kd * 32 + quad * 8];
                yacc[ct] = __builtin_amdgcn_mfma_f32_16x16x32_bf16(pf[kd], vf, yacc[ct], 0, 0, 0);
            }
        }
    }

    // normalize and store y [B,N,128] bf16
    #pragma unroll
    for (int r = 0; r < 4; ++r) {
        float il = 1.0f / li[r];
        int q = n0 + w * 16 + quad * 4 + r;
        unsigned short* yr = yb + ((size_t)b * Nn + q) * Cin;
        #pragma unroll
        for (int ct = 0; ct < 8; ++ct)
            yr[ct * 16 + l16] = f2bf(yacc[ct][r] * il);
    }
}

// ---------------------------------------------------------------------------
// Kernel 3: out = Wbf @ y + cvec + x   (BN pre-folded into Wbf/cvec)
// ---------------------------------------------------------------------------
__global__ __launch_bounds__(256) void k_out(
    const unsigned short* __restrict__ yb, const float* __restrict__ x,
    const unsigned short* __restrict__ Wbf, const float* __restrict__ cvec,
    float* __restrict__ out)
{
    __shared__ __align__(16) unsigned short Ys[64 * DPAD];    // 17.4 KB
    __shared__ __align__(16) unsigned short Ws[128 * DPAD];   // 34.8 KB

    const int t    = threadIdx.x;
    const int w    = t >> 6;
    const int l    = t & 63;
    const int quad = l >> 4;
    const int l16  = l & 15;
    const int b    = blockIdx.x >> 6;
    const int qt   = blockIdx.x & 63;
    const int n0   = qt * 64;

    // stage y tile [64 q x 128 c]
    #pragma unroll
    for (int it = 0; it < 4; ++it) {
        int idx = t + 256 * it;              // 0..1023
        int q = idx >> 4, d8 = idx & 15;
        *(uint4*)&Ys[q * DPAD + d8 * 8] =
            *(const uint4*)&yb[((size_t)b * Nn + n0 + q) * Cin + d8 * 8];
    }

    for (int oc = 0; oc < 2; ++oc) {
        __syncthreads();                      // Ws reuse + (first iter) Ys ready-gate
        // stage W chunk [128 o x 128 c]
        #pragma unroll
        for (int it = 0; it < 8; ++it) {
            int idx = t + 256 * it;          // 0..2047
            int o = idx >> 4, d8 = idx & 15;
            *(uint4*)&Ws[o * DPAD + d8 * 8] =
                *(const uint4*)&Wbf[((size_t)(oc * 128 + o)) * Cin + d8 * 8];
        }
        __syncthreads();

        // A-frags: W rows (m = o), 2 m-tiles per wave
        short8 af[2][4];
        #pragma unroll
        for (int mt = 0; mt < 2; ++mt)
            #pragma unroll
            for (int kd = 0; kd < 4; ++kd)
                af[mt][kd] = *(const short8*)&Ws[(w * 32 + mt * 16 + l16) * DPAD + kd * 32 + quad * 8];

        floatx4 acc[2][4] = {};
        #pragma unroll
        for (int nt = 0; nt < 4; ++nt) {
            short8 bfr[4];
            #pragma unroll
            for (int kd = 0; kd < 4; ++kd)
                bfr[kd] = *(const short8*)&Ys[(nt * 16 + l16) * DPAD + kd * 32 + quad * 8];
            #pragma unroll
            for (int mt = 0; mt < 2; ++mt)
                #pragma unroll
                for (int kd = 0; kd < 4; ++kd)
                    acc[mt][nt] = __builtin_amdgcn_mfma_f32_16x16x32_bf16(af[mt][kd], bfr[kd], acc[mt][nt], 0, 0, 0);
        }

        // epilogue: out = D + cvec[o] + x, coalesced 16-lane 64 B segments
        #pragma unroll
        for (int mt = 0; mt < 2; ++mt) {
            #pragma unroll
            for (int r = 0; r < 4; ++r) {
                int o = oc * 128 + w * 32 + mt * 16 + quad * 4 + r;
                float cv = cvec[o];
                #pragma unroll
                for (int nt = 0; nt < 4; ++nt) {
                    size_t gi = ((size_t)(b * Cc + o)) * Nn + n0 + nt * 16 + l16;
                    out[gi] = acc[mt][nt][r] + cv + x[gi];
                }
            }
        }
    }
}

// ---------------------------------------------------------------------------
extern "C" void kernel_launch(void* const* d_in, const int* in_sizes, int n_in,
                              void* d_out, int out_size, void* d_ws, size_t ws_size,
                              hipStream_t stream) {
    const float* x    = (const float*)d_in[0];
    const float* g_w  = (const float*)d_in[1];
    const float* g_b  = (const float*)d_in[2];
    const float* th_w = (const float*)d_in[3];
    const float* th_b = (const float*)d_in[4];
    const float* ph_w = (const float*)d_in[5];
    const float* ph_b = (const float*)d_in[6];
    const float* W_w  = (const float*)d_in[7];
    const float* W_b  = (const float*)d_in[8];
    const float* gmm  = (const float*)d_in[9];
    const float* bta  = (const float*)d_in[10];
    const float* mmn  = (const float*)d_in[11];
    const float* vvr  = (const float*)d_in[12];
    float* out = (float*)d_out;

    unsigned short* thetaT = (unsigned short*)d_ws;      // 8 MB
    unsigned short* phiPt  = thetaT + (size_t)4194304;   // 2 MB
    unsigned short* gPc    = phiPt + (size_t)1048576;    // 2 MB
    unsigned short* yb     = gPc + (size_t)1048576;      // 8 MB
    unsigned short* Wbf    = yb + (size_t)4194304;       // 64 KB
    unsigned short* gWh    = Wbf + 32768;
    unsigned short* thWh   = gWh + 32768;
    unsigned short* thWl   = thWh + 32768;
    unsigned short* phWh   = thWl + 32768;
    unsigned short* phWl   = phWh + 32768;
    float*          cvec   = (float*)(phWl + 32768);     // 1 KB

    k_prep<<<dim3(512), dim3(256), 0, stream>>>(
        g_w, th_w, ph_w, W_w, W_b, gmm, bta, mmn, vvr,
        gWh, thWh, thWl, phWh, phWl, Wbf, cvec);
    k_conv3<<<dim3(Bn * 64), dim3(256), 0, stream>>>(
        x, gWh, thWh, thWl, phWh, phWl, g_b, th_b, ph_b, thetaT, gPc, phiPt);
    k_attn<<<dim3(Bn * 64), dim3(256), 0, stream>>>(thetaT, phiPt, gPc, yb);
    k_out<<<dim3(Bn * 64), dim3(256), 0, stream>>>(yb, x, Wbf, cvec, out);
}